// Round 6
// baseline (154.640 us; speedup 1.0000x reference)
//
#include <hip/hip_runtime.h>
#include <hip/hip_fp16.h>

// BlockDiagonalLinear hyperbolic layer. Round 6: K1 rebuilt for latency.
//   K0 wrepack: W f32 -> bf16 MFMA fragments [b][kf][nt][lane][8] (2 MiB ws)
//   K1 gemm:   WG=256thr(4 waves)/64 rows/block b. B staged per-kf in LDS
//              (16 KiB, shared by 4 waves) with register double-buffer
//              prefetch; A staged batched (8 loads in flight) into 32 KiB
//              swizzled LDS; ds_read_b128 everywhere in the MFMA loop.
//              48 KiB LDS + launch_bounds(256,3) -> 3 WGs/CU, 170-reg budget.
//   K2 gamma:  reduce 16 block partials -> per-row gamma (8192 rows).
//   K3 apply:  pure streaming: out = gam[row] * f16->f32(mx').

typedef __attribute__((ext_vector_type(8))) short short8;
typedef __attribute__((ext_vector_type(4))) float f32x4;

__device__ __forceinline__ ushort f2bf(float f) {
  uint u = __float_as_uint(f);
  return (ushort)((u + 0x7fffu + ((u >> 16) & 1u)) >> 16);  // RNE
}

__device__ __forceinline__ float gamma_of(float sx, float s2) {
  const float xnorm = sqrtf(sx);
  const float un = fmaxf(xnorm, 1e-5f);
  const float a0 = 0.1f * un;
  const float th = tanhf(fminf(a0, 15.f));
  const float c = th / a0;             // h = c * x
  const float hn = th * (xnorm / a0);  // ||h||
  const float xn = fmaxf(hn, 1e-5f);
  const float sp = sqrtf(s2);          // ||mx'||
  float gt = 0.f;
  if (sp > 0.f) {
    const float s = c * sp;  // ||mx||
    const float xc = fminf(0.1f * xn, 1.f - 1e-5f);
    const float at = 0.5f * logf((1.f + xc) / (1.f - xc));  // artanh
    const float t = (s / xn) * at;
    const float tn = tanhf(fminf(t, 15.f));
    const float alpha = tn / (0.1f * s);  // res_c = alpha * mx
    const float rn = tn * 10.f;           // ||res_c||
    const float nrm = fmaxf(rn, 1e-5f);
    const float proj = (nrm > 9.99f) ? (9.99f / nrm) : 1.f;  // _project
    const float yn = fmaxf(rn * proj, 1e-5f);
    const float yc = fminf(0.1f * yn, 1.f - 1e-5f);
    const float at2 = 0.5f * logf((1.f + yc) / (1.f - yc));
    gt = c * alpha * proj * (at2 / (0.1f * yn));  // logmap0 + fold of c
  }
  return gt;
}

// K0: repack W f32 [16][256][256] -> bf16 wb2[b][kf][nt][lane][8].
__global__ __launch_bounds__(256) void wrepack_kernel(const float* __restrict__ w,
                                                      ushort* __restrict__ wb2) {
  int idx = blockIdx.x * blockDim.x + threadIdx.x;  // 131072
  int lane = idx & 63;
  int nt = (idx >> 6) & 15;
  int kf = (idx >> 10) & 7;
  int blk = idx >> 13;
  int g = lane >> 4, q = lane & 15;
  const float* src = w + ((size_t)blk << 16) + (size_t)(nt * 16 + q) * 256 + kf * 32 + g * 8;
  float4 v0 = *reinterpret_cast<const float4*>(src);
  float4 v1 = *reinterpret_cast<const float4*>(src + 4);
  uint4 p;
  p.x = (uint)f2bf(v0.x) | ((uint)f2bf(v0.y) << 16);
  p.y = (uint)f2bf(v0.z) | ((uint)f2bf(v0.w) << 16);
  p.z = (uint)f2bf(v1.x) | ((uint)f2bf(v1.y) << 16);
  p.w = (uint)f2bf(v1.z) | ((uint)f2bf(v1.w) << 16);
  reinterpret_cast<uint4*>(wb2)[idx] = p;
}

// K1: grid 2048 = 16 blocks x 128 row-groups; 256 thr (4 waves); 64 rows/WG.
// Wave w owns rows w*16..w*16+15; B[kf] staged in LDS shared by all 4 waves.
__global__ __launch_bounds__(256, 3) void k1_kernel(const float* __restrict__ x,
                                                    const ushort* __restrict__ wb2,
                                                    float* __restrict__ ssxP,
                                                    float* __restrict__ sspP,
                                                    ushort* __restrict__ mxw) {
  __shared__ __align__(16) ushort As[64 * 256];  // 32 KiB swizzled bf16 A; fp16 mx' later
  __shared__ __align__(16) ushort Bs[16 * 512];  // 16 KiB: B[kf] frags [nt][lane][8]

  const int tid = threadIdx.x;
  const int w = tid >> 6;
  const int lane = tid & 63;
  const int g = lane >> 4;
  const int q = lane & 15;
  const int b = blockIdx.x & 15;
  const int rg = blockIdx.x >> 4;  // 0..127
  const size_t rowbase = (size_t)rg * 64;
  char* lds = reinterpret_cast<char*>(As);
  char* ldsB = reinterpret_cast<char*>(Bs);

  // ---- Stage A: wave-private 16 rows, 8 loads in flight per half ----
#pragma unroll
  for (int h = 0; h < 2; ++h) {
    float4 va[8];
#pragma unroll
    for (int r = 0; r < 8; ++r)
      va[r] = *reinterpret_cast<const float4*>(
          x + (rowbase + w * 16 + h * 8 + r) * 4096 + b * 256 + lane * 4);
#pragma unroll
    for (int r = 0; r < 8; ++r) {
      const int lrow = w * 16 + h * 8 + r;
      uint2 p;
      p.x = (uint)f2bf(va[r].x) | ((uint)f2bf(va[r].y) << 16);
      p.y = (uint)f2bf(va[r].z) | ((uint)f2bf(va[r].w) << 16);
      uint byte = ((uint)(lrow * 512 + lane * 8)) ^ ((uint)(lrow & 7) << 4);
      *reinterpret_cast<uint2*>(lds + byte) = p;
    }
  }

  // ---- ssx from staged bf16 (own region; wave-coherent, no barrier) ----
  {
    const int row = w * 16 + (lane >> 2);
    const int k4 = lane & 3;
    const uint sw = (uint)(row & 7) << 4;
    float ss = 0.f;
#pragma unroll
    for (int i = 0; i < 8; ++i) {
      uint byte = ((uint)(row * 512 + k4 * 128 + i * 16)) ^ sw;
      short8 v = *reinterpret_cast<const short8*>(lds + byte);
#pragma unroll
      for (int j = 0; j < 8; ++j) {
        float f = __uint_as_float(((uint)(ushort)v[j]) << 16);
        ss += f * f;
      }
    }
    ss += __shfl_xor(ss, 1, 64);
    ss += __shfl_xor(ss, 2, 64);
    if (k4 == 0) ssxP[b * 8192 + rowbase + row] = ss;
  }

  // ---- GEMM: B[kf] via LDS with register double-buffer prefetch ----
  f32x4 acc[16];
#pragma unroll
  for (int nt = 0; nt < 16; ++nt) acc[nt] = (f32x4){0.f, 0.f, 0.f, 0.f};

  const ushort* bsrc = wb2 + ((size_t)b << 16);  // block b: 8 kf x 8192 ushorts
  uint4 pb[4];
#pragma unroll
  for (int u = 0; u < 4; ++u)
    pb[u] = *reinterpret_cast<const uint4*>(bsrc + u * 2048 + tid * 8);

  for (int kf = 0; kf < 8; ++kf) {
    if (kf) __syncthreads();  // all waves done reading Bs[kf-1]
#pragma unroll
    for (int u = 0; u < 4; ++u)
      *reinterpret_cast<uint4*>(Bs + u * 2048 + tid * 8) = pb[u];
    __syncthreads();          // Bs[kf] visible
    if (kf < 7) {
      const ushort* nsrc = bsrc + (kf + 1) * 8192;
#pragma unroll
      for (int u = 0; u < 4; ++u)
        pb[u] = *reinterpret_cast<const uint4*>(nsrc + u * 2048 + tid * 8);
    }
    uint abyte = ((uint)((w * 16 + q) * 512 + kf * 64 + g * 16)) ^ ((uint)(q & 7) << 4);
    short8 afr = *reinterpret_cast<const short8*>(lds + abyte);
#pragma unroll
    for (int nt = 0; nt < 16; ++nt) {
      short8 bfr = *reinterpret_cast<const short8*>(ldsB + nt * 1024 + (lane << 4));
      acc[nt] = __builtin_amdgcn_mfma_f32_16x16x32_bf16(afr, bfr, acc[nt], 0, 0, 0);
    }
  }

  // ---- ssp partials: row = w*16 + g*4 + j, summed over cols (nt,q) ----
  {
    float s[4] = {0.f, 0.f, 0.f, 0.f};
#pragma unroll
    for (int nt = 0; nt < 16; ++nt)
#pragma unroll
      for (int j = 0; j < 4; ++j) s[j] += acc[nt][j] * acc[nt][j];
#pragma unroll
    for (int m = 1; m < 16; m <<= 1)
#pragma unroll
      for (int j = 0; j < 4; ++j) s[j] += __shfl_xor(s[j], m, 64);
    if (q == 0) {
#pragma unroll
      for (int j = 0; j < 4; ++j)
        sspP[b * 8192 + rowbase + w * 16 + g * 4 + j] = s[j];
    }
  }

  // ---- In-place fp16 rebounce into own (dead) A-rows ----
#pragma unroll
  for (int nt = 0; nt < 16; ++nt) {
#pragma unroll
    for (int j = 0; j < 4; ++j) {
      const int row = w * 16 + g * 4 + j;
      const int col = nt * 16 + q;
      uint byte = ((uint)(row * 512 + col * 2)) ^ ((uint)(row & 7) << 4);
      *reinterpret_cast<__half*>(lds + byte) = __float2half(acc[nt][j]);
    }
  }

  // ---- Bulk mx' store: wave-contiguous (own rows only) ----
  {
    const int row = w * 16 + (lane >> 2);
    const int k4 = lane & 3;
    const uint sw = (uint)(row & 7) << 4;
    ushort* dst = mxw + ((size_t)b * 8192 + rowbase + row) * 256 + k4 * 64;
#pragma unroll
    for (int i = 0; i < 8; ++i) {
      uint byte = ((uint)(row * 512 + k4 * 128 + i * 16)) ^ sw;
      short8 v = *reinterpret_cast<const short8*>(lds + byte);
      *reinterpret_cast<short8*>(dst + i * 8) = v;
    }
  }
}

// K2: gamma per row.
__global__ __launch_bounds__(256) void gamma_kernel(const float* __restrict__ ssxP,
                                                    const float* __restrict__ sspP,
                                                    float* __restrict__ gam) {
  const int row = blockIdx.x * 256 + threadIdx.x;
  float sx = 0.f, s2 = 0.f;
#pragma unroll
  for (int bb = 0; bb < 16; ++bb) {
    sx += ssxP[bb * 8192 + row];
    s2 += sspP[bb * 8192 + row];
  }
  gam[row] = gamma_of(sx, s2);
}

// K3: out = gam[row] * mx' (fp16->f32). Dense streaming.
__global__ __launch_bounds__(256) void k3_kernel(const ushort* __restrict__ mxw,
                                                 const float* __restrict__ gam,
                                                 float* __restrict__ out) {
  const int t0 = blockIdx.x * 256 + threadIdx.x;
#pragma unroll 4
  for (int it = 0; it < 16; ++it) {
    const int Q = t0 + it * 524288;  // quad index over 16*8192*64
    const int b = Q >> 19;
    const int r = (Q >> 6) & 8191;
    const int c = (Q & 63) << 2;
    uint2 p = *reinterpret_cast<const uint2*>(mxw + ((size_t)Q << 2));
    const float gv = gam[r];
    __half2 h0 = *reinterpret_cast<__half2*>(&p.x);
    __half2 h1 = *reinterpret_cast<__half2*>(&p.y);
    float2 f0 = __half22float2(h0);
    float2 f1 = __half22float2(h1);
    float4 o;
    o.x = f0.x * gv;
    o.y = f0.y * gv;
    o.z = f1.x * gv;
    o.w = f1.y * gv;
    *reinterpret_cast<float4*>(out + (size_t)r * 4096 + b * 256 + c) = o;
  }
}

// ---------------- Fallback: round-3 fused kernel (2 MiB ws) ----------------
__global__ __launch_bounds__(1024, 4) void hyp_fused(const float* __restrict__ x,
                                                     const ushort* __restrict__ wb2,
                                                     float* __restrict__ out) {
  __shared__ ushort xs[16 * 4096];
  __shared__ float ssxp[16];
  __shared__ float sspm[16][16];
  __shared__ float gamv[16];
  const int tid = threadIdx.x;
  const int w = tid >> 6;
  const int lane = tid & 63;
  const int g = lane >> 4, q = lane & 15;
  const size_t rowbase = (size_t)blockIdx.x * 16;
  {
    const float4* xr = reinterpret_cast<const float4*>(x + (rowbase + w) * 4096);
    char* xrow = reinterpret_cast<char*>(xs);
    const uint sw = (uint)(w & 7) << 4;
    float ss = 0.f;
#pragma unroll
    for (int chunk = 0; chunk < 16; ++chunk) {
      float4 v = xr[chunk * 64 + lane];
      ss += v.x * v.x + v.y * v.y + v.z * v.z + v.w * v.w;
      uint2 p;
      p.x = (uint)f2bf(v.x) | ((uint)f2bf(v.y) << 16);
      p.y = (uint)f2bf(v.z) | ((uint)f2bf(v.w) << 16);
      uint byte = ((uint)(w * 8192 + (chunk * 64 + lane) * 8)) ^ sw;
      *reinterpret_cast<uint2*>(xrow + byte) = p;
    }
#pragma unroll
    for (int m = 32; m; m >>= 1) ss += __shfl_xor(ss, m, 64);
    if (lane == 0) ssxp[w] = ss;
  }
  __syncthreads();
  f32x4 acc[16];
#pragma unroll
  for (int nt = 0; nt < 16; ++nt) acc[nt] = (f32x4){0.f, 0.f, 0.f, 0.f};
  for (int kf = 0; kf < 8; ++kf) {
    uint abyte = ((uint)(q * 8192 + w * 512 + kf * 64 + g * 16)) ^ ((uint)(q & 7) << 4);
    short8 afr = *reinterpret_cast<const short8*>(reinterpret_cast<const char*>(xs) + abyte);
    const ushort* bkf = wb2 + ((((size_t)w * 8 + kf) * 16) << 9) + (lane << 3);
#pragma unroll
    for (int nt = 0; nt < 16; ++nt) {
      short8 bfr = *reinterpret_cast<const short8*>(bkf + (nt << 9));
      acc[nt] = __builtin_amdgcn_mfma_f32_16x16x32_bf16(afr, bfr, acc[nt], 0, 0, 0);
    }
  }
  {
    float s0 = 0.f, s1 = 0.f, s2a = 0.f, s3 = 0.f;
#pragma unroll
    for (int nt = 0; nt < 16; ++nt) {
      f32x4 a = acc[nt];
      s0 += a[0] * a[0]; s1 += a[1] * a[1]; s2a += a[2] * a[2]; s3 += a[3] * a[3];
    }
#pragma unroll
    for (int m = 1; m < 16; m <<= 1) {
      s0 += __shfl_xor(s0, m, 64); s1 += __shfl_xor(s1, m, 64);
      s2a += __shfl_xor(s2a, m, 64); s3 += __shfl_xor(s3, m, 64);
    }
    if (q == 0) {
      sspm[w][g * 4 + 0] = s0; sspm[w][g * 4 + 1] = s1;
      sspm[w][g * 4 + 2] = s2a; sspm[w][g * 4 + 3] = s3;
    }
  }
  __syncthreads();
  if (tid < 16) {
    float s2 = 0.f;
#pragma unroll
    for (int ww = 0; ww < 16; ++ww) s2 += sspm[ww][tid];
    gamv[tid] = gamma_of(ssxp[tid], s2);
  }
  __syncthreads();
  float gr[4];
#pragma unroll
  for (int j = 0; j < 4; ++j) gr[j] = gamv[g * 4 + j];
  float* orow = out + rowbase * 4096 + w * 256;
#pragma unroll
  for (int nt = 0; nt < 16; ++nt) {
    const int col = nt * 16 + q;
    f32x4 a = acc[nt];
#pragma unroll
    for (int j = 0; j < 4; ++j) orow[(size_t)(g * 4 + j) * 4096 + col] = gr[j] * a[j];
  }
}

extern "C" void kernel_launch(void* const* d_in, const int* in_sizes, int n_in,
                              void* d_out, int out_size, void* d_ws, size_t ws_size,
                              hipStream_t stream) {
  const float* x = (const float*)d_in[0];  // [4,2048,4096] f32
  const float* w = (const float*)d_in[1];  // [16,256,256] f32
  float* out = (float*)d_out;              // [4,2048,4096] f32

  const size_t WB = (size_t)2 << 20;                // wb2: 2 MiB
  const size_t SSX_OFF = WB;                        // ssxP: 512 KiB
  const size_t SSP_OFF = WB + ((size_t)512 << 10);  // sspP: 512 KiB
  const size_t GAM_OFF = WB + ((size_t)1 << 20);    // gam: 32 KiB
  const size_t MXW_OFF = (size_t)4 << 20;           // mxw: 64 MiB (16*8192*256 f16)
  const size_t NEED = MXW_OFF + (size_t)16 * 8192 * 256 * 2;

  if (ws_size >= NEED) {
    ushort* wb2 = (ushort*)d_ws;
    float* ssxP = (float*)((char*)d_ws + SSX_OFF);
    float* sspP = (float*)((char*)d_ws + SSP_OFF);
    float* gamv = (float*)((char*)d_ws + GAM_OFF);
    ushort* mxw = (ushort*)((char*)d_ws + MXW_OFF);
    wrepack_kernel<<<512, 256, 0, stream>>>(w, wb2);
    k1_kernel<<<2048, 256, 0, stream>>>(x, wb2, ssxP, sspP, mxw);
    gamma_kernel<<<32, 256, 0, stream>>>(ssxP, sspP, gamv);
    k3_kernel<<<2048, 256, 0, stream>>>(mxw, gamv, out);
  } else if (ws_size >= WB) {
    ushort* wb2 = (ushort*)d_ws;
    wrepack_kernel<<<512, 256, 0, stream>>>(w, wb2);
    hyp_fused<<<512, 1024, 0, stream>>>(x, wb2, out);
  }
}

// Round 7
// 135.324 us; speedup vs baseline: 1.1427x; 1.1427x over previous
//
#include <hip/hip_runtime.h>
#include <hip/hip_fp16.h>

// BlockDiagonalLinear hyperbolic layer. Round 7: barrier-free K1 with
// register-resident double-buffered B and 32x32x16 MFMA.
//   K0 wrepack32: W f32 -> bf16 frags wb3[b][kf16][nt8][lane][8] (2 MiB ws)
//   K1: WG=256 (4 waves), 128 rows/WG, wave owns 32 rows x block b.
//       acc[8] f32x16 (128 VGPR), B double-buffered in regs (64 VGPR),
//       A staged to wave-private 16 KiB LDS (no __syncthreads anywhere),
//       launch_bounds(256,2) -> 256-VGPR budget, 2 WGs/CU (64 KiB LDS).
//   K2 gamma: reduce 16 block partials -> per-row gamma.
//   K3 apply: streaming out = gam[row] * f16->f32(mx').

typedef __attribute__((ext_vector_type(8))) short short8;
typedef __attribute__((ext_vector_type(4))) float f32x4;
typedef __attribute__((ext_vector_type(16))) float f32x16;

__device__ __forceinline__ ushort f2bf(float f) {
  uint u = __float_as_uint(f);
  return (ushort)((u + 0x7fffu + ((u >> 16) & 1u)) >> 16);  // RNE
}

__device__ __forceinline__ float gamma_of(float sx, float s2) {
  const float xnorm = sqrtf(sx);
  const float un = fmaxf(xnorm, 1e-5f);
  const float a0 = 0.1f * un;
  const float th = tanhf(fminf(a0, 15.f));
  const float c = th / a0;             // h = c * x
  const float hn = th * (xnorm / a0);  // ||h||
  const float xn = fmaxf(hn, 1e-5f);
  const float sp = sqrtf(s2);          // ||mx'||
  float gt = 0.f;
  if (sp > 0.f) {
    const float s = c * sp;  // ||mx||
    const float xc = fminf(0.1f * xn, 1.f - 1e-5f);
    const float at = 0.5f * logf((1.f + xc) / (1.f - xc));  // artanh
    const float t = (s / xn) * at;
    const float tn = tanhf(fminf(t, 15.f));
    const float alpha = tn / (0.1f * s);  // res_c = alpha * mx
    const float rn = tn * 10.f;           // ||res_c||
    const float nrm = fmaxf(rn, 1e-5f);
    const float proj = (nrm > 9.99f) ? (9.99f / nrm) : 1.f;  // _project
    const float yn = fmaxf(rn * proj, 1e-5f);
    const float yc = fminf(0.1f * yn, 1.f - 1e-5f);
    const float at2 = 0.5f * logf((1.f + yc) / (1.f - yc));
    gt = c * alpha * proj * (at2 / (0.1f * yn));  // logmap0 + fold of c
  }
  return gt;
}

// K0: repack for 32x32x16. frag(b,kf,nt): lane l, j -> W[b][nt*32+(l&31)][kf*16+(l>>5)*8+j]
__global__ __launch_bounds__(256) void wrepack32(const float* __restrict__ w,
                                                 ushort* __restrict__ wb3) {
  int idx = blockIdx.x * 256 + threadIdx.x;  // 131072
  int lane = idx & 63;
  int nt = (idx >> 6) & 7;
  int kf = (idx >> 9) & 15;
  int b = idx >> 13;
  int n = nt * 32 + (lane & 31);
  int k0 = kf * 16 + (lane >> 5) * 8;
  const float* src = w + ((size_t)b << 16) + (size_t)n * 256 + k0;
  float4 v0 = *reinterpret_cast<const float4*>(src);
  float4 v1 = *reinterpret_cast<const float4*>(src + 4);
  uint4 p;
  p.x = (uint)f2bf(v0.x) | ((uint)f2bf(v0.y) << 16);
  p.y = (uint)f2bf(v0.z) | ((uint)f2bf(v0.w) << 16);
  p.z = (uint)f2bf(v1.x) | ((uint)f2bf(v1.y) << 16);
  p.w = (uint)f2bf(v1.z) | ((uint)f2bf(v1.w) << 16);
  reinterpret_cast<uint4*>(wb3)[idx] = p;
}

// K1: grid 1024 = 16 blocks x 64 row-groups; 256 thr (4 waves); 128 rows/WG.
// Wave w: rows rg*128 + w*32 .. +31, block b. NO BARRIERS.
__global__ __launch_bounds__(256, 2) void k1_kernel(const float* __restrict__ x,
                                                    const ushort* __restrict__ wb3,
                                                    float* __restrict__ ssxP,
                                                    float* __restrict__ sspP,
                                                    ushort* __restrict__ mxw) {
  __shared__ __align__(16) ushort As[4][32 * 256];  // 16 KiB per wave, private

  const int tid = threadIdx.x;
  const int w = tid >> 6;
  const int l = tid & 63;
  const int lo = l & 31;
  const int hi = l >> 5;
  const int b = blockIdx.x & 15;
  const int rg = blockIdx.x >> 4;  // 0..63
  const size_t rowbase = (size_t)rg * 128 + (size_t)w * 32;
  char* lds = reinterpret_cast<char*>(As[w]);

  const ushort* bbase = wb3 + ((size_t)b << 16);  // 16 kf x 8 nt x 512 ushorts

  // ---- B kf=0 prefetch (8 independent 16B L2 loads) ----
  short8 b0[8], b1[8];
#pragma unroll
  for (int nt = 0; nt < 8; ++nt)
    b0[nt] = *reinterpret_cast<const short8*>(bbase + (size_t)nt * 512 + l * 8);

  // ---- Stage A: 32 rows, 2 batches of 16 coalesced dwordx4 (16 KB in flight) ----
#pragma unroll
  for (int hh = 0; hh < 2; ++hh) {
    float4 va[16];
#pragma unroll
    for (int r = 0; r < 16; ++r)
      va[r] = *reinterpret_cast<const float4*>(
          x + (rowbase + hh * 16 + r) * 4096 + b * 256 + l * 4);
#pragma unroll
    for (int r = 0; r < 16; ++r) {
      const int row = hh * 16 + r;
      uint2 p;
      p.x = (uint)f2bf(va[r].x) | ((uint)f2bf(va[r].y) << 16);
      p.y = (uint)f2bf(va[r].z) | ((uint)f2bf(va[r].w) << 16);
      uint byte = ((uint)(row * 512 + l * 8)) ^ ((uint)(row & 7) << 4);
      *reinterpret_cast<uint2*>(lds + byte) = p;
    }
  }

  // ---- GEMM: 16 kf, B double-buffered in registers, A frags from LDS ----
  f32x16 acc[8];
#pragma unroll
  for (int nt = 0; nt < 8; ++nt)
#pragma unroll
    for (int r = 0; r < 16; ++r) acc[nt][r] = 0.f;

  for (int kfp = 0; kfp < 8; ++kfp) {
    const int kfe = kfp * 2;
    // prefetch B for kfe+1 into b1 (overlaps MFMAs below)
#pragma unroll
    for (int nt = 0; nt < 8; ++nt)
      b1[nt] = *reinterpret_cast<const short8*>(
          bbase + ((size_t)(kfe + 1) * 8 + nt) * 512 + l * 8);
    {
      uint abyte = ((uint)(lo * 512 + kfe * 32 + hi * 16)) ^ ((uint)(lo & 7) << 4);
      short8 a = *reinterpret_cast<const short8*>(lds + abyte);
#pragma unroll
      for (int nt = 0; nt < 8; ++nt)
        acc[nt] = __builtin_amdgcn_mfma_f32_32x32x16_bf16(a, b0[nt], acc[nt], 0, 0, 0);
    }
    if (kfp < 7) {
#pragma unroll
      for (int nt = 0; nt < 8; ++nt)
        b0[nt] = *reinterpret_cast<const short8*>(
            bbase + ((size_t)(kfe + 2) * 8 + nt) * 512 + l * 8);
    }
    {
      uint abyte = ((uint)(lo * 512 + (kfe + 1) * 32 + hi * 16)) ^ ((uint)(lo & 7) << 4);
      short8 a = *reinterpret_cast<const short8*>(lds + abyte);
#pragma unroll
      for (int nt = 0; nt < 8; ++nt)
        acc[nt] = __builtin_amdgcn_mfma_f32_32x32x16_bf16(a, b1[nt], acc[nt], 0, 0, 0);
    }
  }

  // ---- ssx from staged bf16 (wave-private LDS) ----
  {
    const int row = l >> 1;
    const int seg = l & 1;
    const uint sw = (uint)(row & 7) << 4;
    float ss = 0.f;
#pragma unroll
    for (int i = 0; i < 16; ++i) {
      uint byte = ((uint)(row * 512 + seg * 256 + i * 16)) ^ sw;
      short8 v = *reinterpret_cast<const short8*>(lds + byte);
#pragma unroll
      for (int j = 0; j < 8; ++j) {
        float f = __uint_as_float(((uint)(ushort)v[j]) << 16);
        ss += f * f;
      }
    }
    ss += __shfl_xor(ss, 1, 64);
    if (seg == 0) ssxP[b * 8192 + rowbase + row] = ss;
  }

  // ---- ssp: per-row sum of acc^2. C layout: col=lo, row=(r&3)+8*(r>>2)+4*hi ----
  {
    float s[16];
#pragma unroll
    for (int r = 0; r < 16; ++r) s[r] = 0.f;
#pragma unroll
    for (int nt = 0; nt < 8; ++nt)
#pragma unroll
      for (int r = 0; r < 16; ++r) s[r] += acc[nt][r] * acc[nt][r];
#pragma unroll
    for (int m = 1; m < 32; m <<= 1)
#pragma unroll
      for (int r = 0; r < 16; ++r) s[r] += __shfl_xor(s[r], m, 64);
    if (lo == 0) {
#pragma unroll
      for (int r = 0; r < 16; ++r) {
        const int row = (r & 3) + 8 * (r >> 2) + 4 * hi;
        sspP[b * 8192 + rowbase + row] = s[r];
      }
    }
  }

  // ---- fp16 rebounce into dead A rows (wave-private) ----
#pragma unroll
  for (int nt = 0; nt < 8; ++nt)
#pragma unroll
    for (int r = 0; r < 16; ++r) {
      const int row = (r & 3) + 8 * (r >> 2) + 4 * hi;
      const int col = nt * 32 + lo;
      uint byte = ((uint)(row * 512 + col * 2)) ^ ((uint)(row & 7) << 4);
      *reinterpret_cast<__half*>(lds + byte) = __float2half(acc[nt][r]);
    }

  // ---- Bulk mx' store: 16 x 1 KiB contiguous ----
#pragma unroll
  for (int i = 0; i < 16; ++i) {
    const int row = i * 2 + hi;
    uint byte = ((uint)(row * 512 + lo * 16)) ^ ((uint)(row & 7) << 4);
    short8 v = *reinterpret_cast<const short8*>(lds + byte);
    *reinterpret_cast<short8*>(mxw + ((size_t)b * 8192 + rowbase + row) * 256 + lo * 8) = v;
  }
}

// K2: gamma per row.
__global__ __launch_bounds__(256) void gamma_kernel(const float* __restrict__ ssxP,
                                                    const float* __restrict__ sspP,
                                                    float* __restrict__ gam) {
  const int row = blockIdx.x * 256 + threadIdx.x;
  float sx = 0.f, s2 = 0.f;
#pragma unroll
  for (int bb = 0; bb < 16; ++bb) {
    sx += ssxP[bb * 8192 + row];
    s2 += sspP[bb * 8192 + row];
  }
  gam[row] = gamma_of(sx, s2);
}

// K3: out = gam[row] * mx' (fp16->f32). Dense streaming.
__global__ __launch_bounds__(256) void k3_kernel(const ushort* __restrict__ mxw,
                                                 const float* __restrict__ gam,
                                                 float* __restrict__ out) {
  const int t0 = blockIdx.x * 256 + threadIdx.x;
#pragma unroll 4
  for (int it = 0; it < 16; ++it) {
    const int Q = t0 + it * 524288;  // quad index over 16*8192*64
    const int b = Q >> 19;
    const int r = (Q >> 6) & 8191;
    const int c = (Q & 63) << 2;
    uint2 p = *reinterpret_cast<const uint2*>(mxw + ((size_t)Q << 2));
    const float gv = gam[r];
    __half2 h0 = *reinterpret_cast<__half2*>(&p.x);
    __half2 h1 = *reinterpret_cast<__half2*>(&p.y);
    float2 f0 = __half22float2(h0);
    float2 f1 = __half22float2(h1);
    float4 o;
    o.x = f0.x * gv;
    o.y = f0.y * gv;
    o.z = f1.x * gv;
    o.w = f1.y * gv;
    *reinterpret_cast<float4*>(out + (size_t)r * 4096 + b * 256 + c) = o;
  }
}

// -------- Fallback: round-3 fused kernel + its 16x16 repack (2 MiB ws) --------
__global__ __launch_bounds__(256) void wrepack16(const float* __restrict__ w,
                                                 ushort* __restrict__ wb2) {
  int idx = blockIdx.x * blockDim.x + threadIdx.x;  // 131072
  int lane = idx & 63;
  int nt = (idx >> 6) & 15;
  int kf = (idx >> 10) & 7;
  int blk = idx >> 13;
  int g = lane >> 4, q = lane & 15;
  const float* src = w + ((size_t)blk << 16) + (size_t)(nt * 16 + q) * 256 + kf * 32 + g * 8;
  float4 v0 = *reinterpret_cast<const float4*>(src);
  float4 v1 = *reinterpret_cast<const float4*>(src + 4);
  uint4 p;
  p.x = (uint)f2bf(v0.x) | ((uint)f2bf(v0.y) << 16);
  p.y = (uint)f2bf(v0.z) | ((uint)f2bf(v0.w) << 16);
  p.z = (uint)f2bf(v1.x) | ((uint)f2bf(v1.y) << 16);
  p.w = (uint)f2bf(v1.z) | ((uint)f2bf(v1.w) << 16);
  reinterpret_cast<uint4*>(wb2)[idx] = p;
}

__global__ __launch_bounds__(1024, 4) void hyp_fused(const float* __restrict__ x,
                                                     const ushort* __restrict__ wb2,
                                                     float* __restrict__ out) {
  __shared__ ushort xs[16 * 4096];
  __shared__ float ssxp[16];
  __shared__ float sspm[16][16];
  __shared__ float gamv[16];
  const int tid = threadIdx.x;
  const int w = tid >> 6;
  const int lane = tid & 63;
  const int g = lane >> 4, q = lane & 15;
  const size_t rowbase = (size_t)blockIdx.x * 16;
  {
    const float4* xr = reinterpret_cast<const float4*>(x + (rowbase + w) * 4096);
    char* xrow = reinterpret_cast<char*>(xs);
    const uint sw = (uint)(w & 7) << 4;
    float ss = 0.f;
#pragma unroll
    for (int chunk = 0; chunk < 16; ++chunk) {
      float4 v = xr[chunk * 64 + lane];
      ss += v.x * v.x + v.y * v.y + v.z * v.z + v.w * v.w;
      uint2 p;
      p.x = (uint)f2bf(v.x) | ((uint)f2bf(v.y) << 16);
      p.y = (uint)f2bf(v.z) | ((uint)f2bf(v.w) << 16);
      uint byte = ((uint)(w * 8192 + (chunk * 64 + lane) * 8)) ^ sw;
      *reinterpret_cast<uint2*>(xrow + byte) = p;
    }
#pragma unroll
    for (int m = 32; m; m >>= 1) ss += __shfl_xor(ss, m, 64);
    if (lane == 0) ssxp[w] = ss;
  }
  __syncthreads();
  f32x4 acc[16];
#pragma unroll
  for (int nt = 0; nt < 16; ++nt) acc[nt] = (f32x4){0.f, 0.f, 0.f, 0.f};
  for (int kf = 0; kf < 8; ++kf) {
    uint abyte = ((uint)(q * 8192 + w * 512 + kf * 64 + g * 16)) ^ ((uint)(q & 7) << 4);
    short8 afr = *reinterpret_cast<const short8*>(reinterpret_cast<const char*>(xs) + abyte);
    const ushort* bkf = wb2 + ((((size_t)w * 8 + kf) * 16) << 9) + (lane << 3);
#pragma unroll
    for (int nt = 0; nt < 16; ++nt) {
      short8 bfr = *reinterpret_cast<const short8*>(bkf + (nt << 9));
      acc[nt] = __builtin_amdgcn_mfma_f32_16x16x32_bf16(afr, bfr, acc[nt], 0, 0, 0);
    }
  }
  {
    float s0 = 0.f, s1 = 0.f, s2a = 0.f, s3 = 0.f;
#pragma unroll
    for (int nt = 0; nt < 16; ++nt) {
      f32x4 a = acc[nt];
      s0 += a[0] * a[0]; s1 += a[1] * a[1]; s2a += a[2] * a[2]; s3 += a[3] * a[3];
    }
#pragma unroll
    for (int m = 1; m < 16; m <<= 1) {
      s0 += __shfl_xor(s0, m, 64); s1 += __shfl_xor(s1, m, 64);
      s2a += __shfl_xor(s2a, m, 64); s3 += __shfl_xor(s3, m, 64);
    }
    if (q == 0) {
      sspm[w][g * 4 + 0] = s0; sspm[w][g * 4 + 1] = s1;
      sspm[w][g * 4 + 2] = s2a; sspm[w][g * 4 + 3] = s3;
    }
  }
  __syncthreads();
  if (tid < 16) {
    float s2 = 0.f;
#pragma unroll
    for (int ww = 0; ww < 16; ++ww) s2 += sspm[ww][tid];
    gamv[tid] = gamma_of(ssxp[tid], s2);
  }
  __syncthreads();
  float gr[4];
#pragma unroll
  for (int j = 0; j < 4; ++j) gr[j] = gamv[g * 4 + j];
  float* orow = out + rowbase * 4096 + w * 256;
#pragma unroll
  for (int nt = 0; nt < 16; ++nt) {
    const int col = nt * 16 + q;
    f32x4 a = acc[nt];
#pragma unroll
    for (int j = 0; j < 4; ++j) orow[(size_t)(g * 4 + j) * 4096 + col] = gr[j] * a[j];
  }
}

extern "C" void kernel_launch(void* const* d_in, const int* in_sizes, int n_in,
                              void* d_out, int out_size, void* d_ws, size_t ws_size,
                              hipStream_t stream) {
  const float* x = (const float*)d_in[0];  // [4,2048,4096] f32
  const float* w = (const float*)d_in[1];  // [16,256,256] f32
  float* out = (float*)d_out;              // [4,2048,4096] f32

  const size_t WB = (size_t)2 << 20;                // wb3/wb2: 2 MiB
  const size_t SSX_OFF = WB;                        // ssxP: 512 KiB
  const size_t SSP_OFF = WB + ((size_t)512 << 10);  // sspP: 512 KiB
  const size_t GAM_OFF = WB + ((size_t)1 << 20);    // gam: 32 KiB
  const size_t MXW_OFF = (size_t)4 << 20;           // mxw: 64 MiB
  const size_t NEED = MXW_OFF + (size_t)16 * 8192 * 256 * 2;

  if (ws_size >= NEED) {
    ushort* wb3 = (ushort*)d_ws;
    float* ssxP = (float*)((char*)d_ws + SSX_OFF);
    float* sspP = (float*)((char*)d_ws + SSP_OFF);
    float* gamv = (float*)((char*)d_ws + GAM_OFF);
    ushort* mxw = (ushort*)((char*)d_ws + MXW_OFF);
    wrepack32<<<512, 256, 0, stream>>>(w, wb3);
    k1_kernel<<<1024, 256, 0, stream>>>(x, wb3, ssxP, sspP, mxw);
    gamma_kernel<<<32, 256, 0, stream>>>(ssxP, sspP, gamv);
    k3_kernel<<<2048, 256, 0, stream>>>(mxw, gamv, out);
  } else if (ws_size >= WB) {
    ushort* wb2 = (ushort*)d_ws;
    wrepack16<<<512, 256, 0, stream>>>(w, wb2);
    hyp_fused<<<512, 1024, 0, stream>>>(x, wb2, out);
  }
}